// Round 19
// baseline (308.808 us; speedup 1.0000x reference)
//
#include <hip/hip_runtime.h>

#define D 128
#define NEG_SLOPE 0.2f

typedef __attribute__((ext_vector_type(8))) short short8;
typedef __attribute__((ext_vector_type(4))) float f32x4;

__device__ __forceinline__ float wred_sum(float v){
#pragma unroll
  for (int m = 32; m; m >>= 1) v += __shfl_xor(v, m);
  return v;
}
__device__ __forceinline__ int wred_sumi(int v){
#pragma unroll
  for (int m = 32; m; m >>= 1) v += __shfl_xor(v, m);
  return v;
}
__device__ __forceinline__ float wred_max(float v){
#pragma unroll
  for (int m = 32; m; m >>= 1) v = fmaxf(v, __shfl_xor(v, m));
  return v;
}
__device__ __forceinline__ unsigned short bf16r(float f){
  unsigned int u = __float_as_uint(f);
  u += 0x7fffu + ((u >> 16) & 1u);
  return (unsigned short)(u >> 16);
}
__device__ __forceinline__ float bf2f(unsigned int hi16){
  return __uint_as_float(hi16 << 16);
}

// K1: weight prep (bf16 transposes + we = W_edge@att_edge) + zero cnt  (~8us)
__global__ void k_prep0(const float* __restrict__ W_lin, const float* __restrict__ W1,
                        const float* __restrict__ W2, const float* __restrict__ W_edge,
                        const float* __restrict__ att_edge,
                        unsigned short* __restrict__ Wlt, unsigned short* __restrict__ W1t,
                        unsigned short* __restrict__ W2t, float* __restrict__ we,
                        int* __restrict__ cnt, int N){
  int t = blockIdx.x * blockDim.x + threadIdx.x;
  if (t < N) cnt[t] = 0;
  if (t < 128 * 128){
    int c = t >> 7, k = t & 127;
    Wlt[t] = bf16r(W_lin[k * 128 + c]);
  } else if (t < 128 * 128 + 512 * 128){
    int u = t - 128 * 128; int c = u >> 7, k = u & 127;
    W1t[u] = bf16r(W1[k * 512 + c]);
  } else if (t < 128 * 128 + 512 * 128 + 128 * 512){
    int u = t - (128 * 128 + 512 * 128); int c = u >> 9, k = u & 511;
    W2t[u] = bf16r(W2[k * 128 + c]);
  } else {
    int u = t - (128 * 128 + 512 * 128 + 128 * 512);
    if (u < 128){
      float s = 0.f;
      for (int j = 0; j < 128; ++j) s += W_edge[u * 128 + j] * att_edge[j];
      we[u] = s;
    }
  }
}

// K2: LN1 + h = xn @ W_lin (Wlt in swizzled LDS) -> hq, dots, degree count
__global__ __launch_bounds__(256) void k_hgemm(const float* __restrict__ x,
                                               const unsigned short* __restrict__ Wlt,
                                               const float* __restrict__ ln1_g,
                                               const float* __restrict__ ln1_b,
                                               const float* __restrict__ att_src,
                                               const float* __restrict__ att_dst,
                                               const int* __restrict__ ei,
                                               unsigned short* __restrict__ hq,
                                               float* __restrict__ asrc,
                                               float* __restrict__ adst,
                                               int* __restrict__ cnt, int N, int E){
  __shared__ unsigned short wbuf[16384];   // 32KB swizzled copy of Wlt
#pragma unroll
  for (int r = 0; r < 8; ++r){
    int idx = r * 256 + threadIdx.x;
    int c = idx >> 4, kc = idx & 15;
    short8 w = *(const short8*)(Wlt + c * 128 + kc * 8);
    *(short8*)((char*)wbuf + c * 256 + ((kc * 16) ^ ((c & 7) << 4))) = w;
  }
  __syncthreads();
  int wid = threadIdx.x >> 6, lane = threadIdx.x & 63;
  int rb = blockIdx.x * 64 + wid * 16;
  int row = rb + (lane & 15);
  int rowc = row < N ? row : N - 1;
  int ksub = (lane >> 4) * 8;
  float v[4][8];
#pragma unroll
  for (int kb = 0; kb < 4; ++kb){
    float4 p0 = *(const float4*)(x + (size_t)rowc * 128 + kb * 32 + ksub);
    float4 p1 = *(const float4*)(x + (size_t)rowc * 128 + kb * 32 + ksub + 4);
    v[kb][0]=p0.x; v[kb][1]=p0.y; v[kb][2]=p0.z; v[kb][3]=p0.w;
    v[kb][4]=p1.x; v[kb][5]=p1.y; v[kb][6]=p1.z; v[kb][7]=p1.w;
  }
  float s = 0.f;
#pragma unroll
  for (int kb = 0; kb < 4; ++kb)
#pragma unroll
    for (int j = 0; j < 8; ++j) s += v[kb][j];
  s += __shfl_xor(s, 16); s += __shfl_xor(s, 32);
  float mu = s * (1.0f / 128.f);
  float q = 0.f;
#pragma unroll
  for (int kb = 0; kb < 4; ++kb)
#pragma unroll
    for (int j = 0; j < 8; ++j){ float d = v[kb][j] - mu; q += d * d; }
  q += __shfl_xor(q, 16); q += __shfl_xor(q, 32);
  float rstd = rsqrtf(q * (1.0f / 128.f) + 1e-5f);
  short8 a[4];
#pragma unroll
  for (int kb = 0; kb < 4; ++kb){
    float4 g0 = *(const float4*)(ln1_g + kb * 32 + ksub);
    float4 g1 = *(const float4*)(ln1_g + kb * 32 + ksub + 4);
    float4 b0 = *(const float4*)(ln1_b + kb * 32 + ksub);
    float4 b1 = *(const float4*)(ln1_b + kb * 32 + ksub + 4);
    float gg[8] = {g0.x,g0.y,g0.z,g0.w,g1.x,g1.y,g1.z,g1.w};
    float bb[8] = {b0.x,b0.y,b0.z,b0.w,b1.x,b1.y,b1.z,b1.w};
#pragma unroll
    for (int j = 0; j < 8; ++j)
      a[kb][j] = (short)bf16r((v[kb][j] - mu) * rstd * gg[j] + bb[j]);
  }
  f32x4 acc[8];
#pragma unroll
  for (int ct = 0; ct < 8; ++ct) acc[ct] = (f32x4){0.f, 0.f, 0.f, 0.f};
#pragma unroll
  for (int ct = 0; ct < 8; ++ct){
    int col = ct * 16 + (lane & 15);
    int cswz = (col & 7) << 4;
#pragma unroll
    for (int kb = 0; kb < 4; ++kb){
      short8 bf = *(const short8*)((const char*)wbuf + col * 256 +
                                   ((kb * 64 + ksub * 2) ^ cswz));
      acc[ct] = __builtin_amdgcn_mfma_f32_16x16x32_bf16(a[kb], bf, acc[ct], 0, 0, 0);
    }
  }
  int r0 = rb + (lane >> 4) * 4;
#pragma unroll
  for (int ct = 0; ct < 8; ++ct){
    int col = ct * 16 + (lane & 15);
#pragma unroll
    for (int j = 0; j < 4; ++j){
      int r = r0 + j;
      if (r < N) hq[(size_t)r * 128 + col] = bf16r(acc[ct][j]);
    }
  }
  float as_v[8], ad_v[8];
#pragma unroll
  for (int ct = 0; ct < 8; ++ct){
    int col = ct * 16 + (lane & 15);
    as_v[ct] = att_src[col];
    ad_v[ct] = att_dst[col];
  }
  float ps[4] = {0.f,0.f,0.f,0.f}, pd[4] = {0.f,0.f,0.f,0.f};
#pragma unroll
  for (int ct = 0; ct < 8; ++ct)
#pragma unroll
    for (int j = 0; j < 4; ++j){
      ps[j] += acc[ct][j] * as_v[ct];
      pd[j] += acc[ct][j] * ad_v[ct];
    }
#pragma unroll
  for (int m = 1; m < 16; m <<= 1)
#pragma unroll
    for (int j = 0; j < 4; ++j){
      ps[j] += __shfl_xor(ps[j], m);
      pd[j] += __shfl_xor(pd[j], m);
    }
  if ((lane & 15) == 0){
#pragma unroll
    for (int j = 0; j < 4; ++j){
      int r = r0 + j;
      if (r < N){ asrc[r] = ps[j]; adst[r] = pd[j]; }
    }
  }
  int t = blockIdx.x * blockDim.x + threadIdx.x;
  int stride = gridDim.x * blockDim.x;
  for (int e = t; e < E; e += stride) atomicAdd(&cnt[ei[E + e]], 1);
}

// K3: exclusive scan (self-sufficient, one node)
__global__ void k_escan(const int* __restrict__ cnt, int* __restrict__ start,
                        int* __restrict__ cursor, int N){
  int b = blockIdx.x, t = threadIdx.x;
  int base = b * 256;
  int acc = 0;
  for (int i = t; i < base; i += 256) acc += cnt[i];
  acc = wred_sumi(acc);
  __shared__ int wsum[4];
  if ((t & 63) == 0) wsum[t >> 6] = acc;
  __syncthreads();
  int s_off = wsum[0] + wsum[1] + wsum[2] + wsum[3];
  int i = base + t;
  int c = (i < N) ? cnt[i] : 0;
  __shared__ int sd[256];
  sd[t] = c;
  __syncthreads();
  for (int off = 1; off < 256; off <<= 1){
    int vv = (t >= off) ? sd[t - off] : 0;
    __syncthreads();
    sd[t] += vv;
    __syncthreads();
  }
  int st = s_off + sd[t] - c;
  if (i <= N) start[i] = st;
  if (i < N) cursor[i] = st;
}

// K4: fused edge logits + CSR scatter — at HBM roofline (~51us)
__global__ void k_edge_scatter(const float* __restrict__ ea, const int* __restrict__ ei,
                               const float* __restrict__ we, const float* __restrict__ asrc,
                               const float* __restrict__ adst, int* __restrict__ cursor,
                               int2* __restrict__ esa, int E){
  int gw = (blockIdx.x * blockDim.x + threadIdx.x) >> 6;
  int lane = threadIdx.x & 63;
  int e = gw * 2 + (lane >> 5);
  int li = lane & 31;
  if (e >= E) return;
  float4 v = *(const float4*)(ea + (size_t)e * 128 + li * 4);
  float4 w = *(const float4*)(we + li * 4);
  float s = v.x * w.x + v.y * w.y + v.z * w.z + v.w * w.w;
#pragma unroll
  for (int m = 16; m; m >>= 1) s += __shfl_xor(s, m);
  if (li == 0){
    int sn = ei[e], dn = ei[E + e];
    float al = asrc[sn] + adst[dn] + s;
    al = al > 0.f ? al : NEG_SLOPE * al;
    int slot = atomicAdd(&cursor[dn], 1);
    esa[slot] = make_int2(sn, __float_as_int(al));
  }
}

// K5: per-node softmax + gather + residual + LN2 — 8-wide unrolled gather
__global__ void k_agg(const float* __restrict__ x, const unsigned short* __restrict__ hq,
                      const int* __restrict__ start, const int2* __restrict__ esa,
                      const float* __restrict__ gat_bias,
                      const float* __restrict__ g2, const float* __restrict__ b2,
                      float* __restrict__ out, unsigned short* __restrict__ xn2q, int N){
  int n = (blockIdx.x * blockDim.x + threadIdx.x) >> 6;
  int lane = threadIdx.x & 63;
  if (n >= N) return;
  int beg = start[n], end = start[n + 1];
  float m = -1e30f;
  for (int i = beg + lane; i < end; i += 64) m = fmaxf(m, __int_as_float(esa[i].y));
  m = wred_max(m);
  float dsv[8] = {0,0,0,0,0,0,0,0};
  float a0v[8] = {0,0,0,0,0,0,0,0};
  float a1v[8] = {0,0,0,0,0,0,0,0};
  int s = beg;
  for (; s + 8 <= end; s += 8){
    int2 ev[8];
#pragma unroll
    for (int u = 0; u < 8; ++u) ev[u] = esa[s + u];
    float xv[8];
    unsigned int hv[8];
#pragma unroll
    for (int u = 0; u < 8; ++u){
      xv[u] = __expf(__int_as_float(ev[u].y) - m);
      hv[u] = *(const unsigned int*)(hq + (size_t)ev[u].x * 128 + lane * 2);
    }
#pragma unroll
    for (int u = 0; u < 8; ++u){
      dsv[u] += xv[u];
      a0v[u] += xv[u] * bf2f(hv[u] & 0xffffu);
      a1v[u] += xv[u] * bf2f(hv[u] >> 16);
    }
  }
  for (; s < end; ++s){
    int2 ev = esa[s];
    float ex = __expf(__int_as_float(ev.y) - m);
    unsigned int hv = *(const unsigned int*)(hq + (size_t)ev.x * 128 + lane * 2);
    dsv[0] += ex;
    a0v[0] += ex * bf2f(hv & 0xffffu);
    a1v[0] += ex * bf2f(hv >> 16);
  }
  float ds = ((dsv[0]+dsv[1])+(dsv[2]+dsv[3])) + ((dsv[4]+dsv[5])+(dsv[6]+dsv[7]));
  float a0 = ((a0v[0]+a0v[1])+(a0v[2]+a0v[3])) + ((a0v[4]+a0v[5])+(a0v[6]+a0v[7]));
  float a1 = ((a1v[0]+a1v[1])+(a1v[2]+a1v[3])) + ((a1v[4]+a1v[5])+(a1v[6]+a1v[7]));
  float inv = (end > beg) ? 1.f / fmaxf(ds, 1e-16f) : 0.f;
  a0 *= inv; a1 *= inv;
  float2 xv  = *(const float2*)(x + (size_t)n * 128 + lane * 2);
  float2 gbv = *(const float2*)(gat_bias + lane * 2);
  float r0 = xv.x + a0 + gbv.x;
  float r1 = xv.y + a1 + gbv.y;
  float mu = wred_sum(r0 + r1) * (1.0f / 128.f);
  float d0 = r0 - mu, d1 = r1 - mu;
  float var = wred_sum(d0 * d0 + d1 * d1) * (1.0f / 128.f);
  float rstd = rsqrtf(var + 1e-5f);
  float2 gv = *(const float2*)(g2 + lane * 2);
  float2 bv = *(const float2*)(b2 + lane * 2);
  float o0 = d0 * rstd * gv.x + bv.x;
  float o1 = d1 * rstd * gv.y + bv.y;
  *(float2*)(out + (size_t)n * 128 + lane * 2) = make_float2(r0, r1);
  unsigned int pk = (unsigned int)bf16r(o0) | ((unsigned int)bf16r(o1) << 16);
  *(unsigned int*)(xn2q + (size_t)n * 128 + lane * 2) = pk;
}

// K6: FFN v5.1 — v5 + software pipeline: [B(t-1) || stage(t)] -> sync -> A(t)
// -> sync. 2 barriers/tile (was 3), xn-tile HBM latency hidden under B's MFMAs.
// Same arithmetic/order as v5 (bit-exact). LDS 80KB, 512 thr -> 2 blocks/CU.
__global__ __launch_bounds__(512) void k_ffn(const unsigned short* __restrict__ xn2q,
                                             const unsigned short* __restrict__ W1t,
                                             const unsigned short* __restrict__ W2t,
                                             const float* __restrict__ b1,
                                             const float* __restrict__ b2,
                                             float* __restrict__ out, int N, int T){
  __shared__ unsigned short w1lds[128 * 128];  // 32KB [hcol_local][k] swizzled
  __shared__ unsigned short w2lds[128 * 128];  // 32KB [ocol][klocal] swizzled
  __shared__ unsigned short xnt[32 * 128];     // 8KB  [row][k] swizzled
  __shared__ unsigned short hidt[32 * 128];    // 8KB  [row][hcol_local] swizzled
  const int tid = threadIdx.x;
  const int chunk = blockIdx.x & 3;
  const int tb0 = blockIdx.x >> 2;             // 0..127
#pragma unroll
  for (int r = 0; r < 8; ++r){
    int idx = r * 512 + tid;                   // 4096: [w sel][cl(128)][kc(16)]
    int cl = (idx >> 4) & 127, kc = idx & 15;
    int dst = cl * 256 + ((kc * 16) ^ ((cl & 7) << 4));
    if (idx < 2048){
      short8 w1v = *(const short8*)(W1t + (size_t)(chunk * 128 + cl) * 128 + kc * 8);
      *(short8*)((char*)w1lds + dst) = w1v;
    } else {
      short8 w2v = *(const short8*)(W2t + (size_t)cl * 512 + chunk * 128 + kc * 8);
      *(short8*)((char*)w2lds + dst) = w2v;
    }
  }
  const int wid = tid >> 6, lane = tid & 63;
  const int i = lane & 15, g = lane >> 4;
  const int rw = wid >> 2;          // 0..1: 16-row half
  const int ca = wid & 3;           // 0..3: 32-col slice
  const int srow = tid >> 4, skc = tid & 15;   // staging coords

  // phase A: xnt -> hidt (relu(xn@W1c+b1c))
  auto phaseA = [&](){
#pragma unroll
    for (int ct = 0; ct < 2; ++ct){
      int hcol = ca * 32 + ct * 16 + i;
      int cswz = (hcol & 7) << 4;
      f32x4 hacc = {0.f, 0.f, 0.f, 0.f};
#pragma unroll
      for (int kb = 0; kb < 4; ++kb){
        int arow = rw * 16 + i;
        short8 af = *(const short8*)((const char*)xnt + arow * 256 +
                                     ((kb * 64 + g * 16) ^ ((arow & 7) << 4)));
        short8 bf = *(const short8*)((const char*)w1lds + hcol * 256 +
                                     ((kb * 64 + g * 16) ^ cswz));
        hacc = __builtin_amdgcn_mfma_f32_16x16x32_bf16(af, bf, hacc, 0, 0, 0);
      }
      float bias = b1[chunk * 128 + hcol];
#pragma unroll
      for (int j = 0; j < 4; ++j){
        float v = hacc[j] + bias;
        v = v > 0.f ? v : 0.f;
        int nl = rw * 16 + g * 4 + j;
        *(unsigned short*)((char*)hidt + nl * 256 + ((hcol * 2) ^ ((nl & 7) << 4))) = bf16r(v);
      }
    }
  };
  // phase B: hidt -> atomic out for tile t
  auto phaseB = [&](int t){
#pragma unroll
    for (int ct = 0; ct < 2; ++ct){
      int ocol = ca * 32 + ct * 16 + i;
      int cswz = (ocol & 7) << 4;
      f32x4 oacc = {0.f, 0.f, 0.f, 0.f};
#pragma unroll
      for (int kbl = 0; kbl < 4; ++kbl){
        int nrow = rw * 16 + i;
        short8 af = *(const short8*)((const char*)hidt + nrow * 256 +
                                     ((kbl * 64 + g * 16) ^ ((nrow & 7) << 4)));
        short8 bf = *(const short8*)((const char*)w2lds + ocol * 256 +
                                     ((kbl * 64 + g * 16) ^ cswz));
        oacc = __builtin_amdgcn_mfma_f32_16x16x32_bf16(af, bf, oacc, 0, 0, 0);
      }
      float bias = (chunk == 0) ? b2[ocol] : 0.f;
#pragma unroll
      for (int j = 0; j < 4; ++j){
        int row = t * 32 + rw * 16 + g * 4 + j;
        if (row < N) atomicAdd(&out[(size_t)row * 128 + ocol], oacc[j] + bias);
      }
    }
  };
  auto stage_load = [&](int t)->short8 {
    int trow = t * 32 + srow;
    int trc = trow < N ? trow : N - 1;
    return *(const short8*)(xn2q + (size_t)trc * 128 + skc * 8);
  };
  auto stage_write = [&](short8 xv){
    *(short8*)((char*)xnt + srow * 256 + ((skc * 16) ^ ((srow & 7) << 4))) = xv;
  };

  // prologue (tb0 < 128 <= T always for N=50000)
  int t = tb0;
  {
    short8 xv = stage_load(t);
    stage_write(xv);
  }
  __syncthreads();   // also covers weight staging
  phaseA();
  __syncthreads();
  for (int tn = t + 128; tn < T; tn += 128){
    short8 xv = stage_load(tn);   // issue loads early
    phaseB(t);                    // overlap with load latency
    stage_write(xv);              // land staged tile (xnt free: A(t) done)
    __syncthreads();
    phaseA();
    __syncthreads();
    t = tn;
  }
  phaseB(t);
}

extern "C" void kernel_launch(void* const* d_in, const int* in_sizes, int n_in,
                              void* d_out, int out_size, void* d_ws, size_t ws_size,
                              hipStream_t stream){
  const float* x        = (const float*)d_in[0];
  const int*   ei       = (const int*)  d_in[1];
  const float* ea       = (const float*)d_in[2];
  const float* ln1_g    = (const float*)d_in[3];
  const float* ln1_b    = (const float*)d_in[4];
  const float* W_lin    = (const float*)d_in[5];
  const float* att_src  = (const float*)d_in[6];
  const float* att_dst  = (const float*)d_in[7];
  const float* W_edge   = (const float*)d_in[8];
  const float* att_edge = (const float*)d_in[9];
  const float* gat_bias = (const float*)d_in[10];
  const float* ln2_g    = (const float*)d_in[11];
  const float* ln2_b    = (const float*)d_in[12];
  const float* W1       = (const float*)d_in[13];
  const float* b1       = (const float*)d_in[14];
  const float* W2       = (const float*)d_in[15];
  const float* b2       = (const float*)d_in[16];

  const int N = in_sizes[0] / 128;
  const int E = in_sizes[2] / 128;
  const int T32 = (N + 31) / 32;
  float* out = (float*)d_out;

  char* pp = (char*)d_ws;
  auto carve = [&](size_t bytes) -> char* {
    char* r = pp; pp += (bytes + 255) & ~(size_t)255; return r;
  };
  unsigned short* hq     = (unsigned short*)carve((size_t)N * 128 * 2);
  unsigned short* xn2q   = (unsigned short*)carve((size_t)N * 128 * 2);
  float*          asrc   = (float*)carve((size_t)N * 4);
  float*          adst   = (float*)carve((size_t)N * 4);
  int2*           esa    = (int2*)carve((size_t)E * 8);
  int*            cnt    = (int*)carve((size_t)N * 4);
  int*            cursor = (int*)carve((size_t)N * 4);
  int*            start  = (int*)carve((size_t)(N + 1) * 4);
  unsigned short* Wlt    = (unsigned short*)carve(128 * 128 * 2);
  unsigned short* W1t    = (unsigned short*)carve(512 * 128 * 2);
  unsigned short* W2t    = (unsigned short*)carve(128 * 512 * 2);
  float*          we     = (float*)carve(128 * 4);

  k_prep0<<<(128*128 + 512*128 + 128*512 + 128 + 255) / 256, 256, 0, stream>>>(
      W_lin, W1, W2, W_edge, att_edge, Wlt, W1t, W2t, we, cnt, N);
  k_hgemm<<<(N + 63) / 64, 256, 0, stream>>>(x, Wlt, ln1_g, ln1_b, att_src, att_dst, ei,
                                             hq, asrc, adst, cnt, N, E);
  k_escan<<<N / 256 + 1, 256, 0, stream>>>(cnt, start, cursor, N);
  k_edge_scatter<<<(E + 7) / 8, 256, 0, stream>>>(ea, ei, we, asrc, adst, cursor, esa, E);
  k_agg<<<(N + 3) / 4, 256, 0, stream>>>(x, hq, start, esa, gat_bias, ln2_g, ln2_b,
                                         out, xn2q, N);
  k_ffn<<<512, 512, 0, stream>>>(xn2q, W1t, W2t, b1, b2, out, N, T32);
}

// Round 20
// 301.855 us; speedup vs baseline: 1.0230x; 1.0230x over previous
//
#include <hip/hip_runtime.h>

#define D 128
#define NEG_SLOPE 0.2f

typedef __attribute__((ext_vector_type(8))) short short8;
typedef __attribute__((ext_vector_type(4))) float f32x4;

__device__ __forceinline__ float wred_sum(float v){
#pragma unroll
  for (int m = 32; m; m >>= 1) v += __shfl_xor(v, m);
  return v;
}
__device__ __forceinline__ int wred_sumi(int v){
#pragma unroll
  for (int m = 32; m; m >>= 1) v += __shfl_xor(v, m);
  return v;
}
__device__ __forceinline__ float wred_max(float v){
#pragma unroll
  for (int m = 32; m; m >>= 1) v = fmaxf(v, __shfl_xor(v, m));
  return v;
}
__device__ __forceinline__ unsigned short bf16r(float f){
  unsigned int u = __float_as_uint(f);
  u += 0x7fffu + ((u >> 16) & 1u);
  return (unsigned short)(u >> 16);
}
__device__ __forceinline__ float bf2f(unsigned int hi16){
  return __uint_as_float(hi16 << 16);
}

// K1: weight prep (bf16 transposes + we = W_edge@att_edge) + zero cnt  (~8us)
__global__ void k_prep0(const float* __restrict__ W_lin, const float* __restrict__ W1,
                        const float* __restrict__ W2, const float* __restrict__ W_edge,
                        const float* __restrict__ att_edge,
                        unsigned short* __restrict__ Wlt, unsigned short* __restrict__ W1t,
                        unsigned short* __restrict__ W2t, float* __restrict__ we,
                        int* __restrict__ cnt, int N){
  int t = blockIdx.x * blockDim.x + threadIdx.x;
  if (t < N) cnt[t] = 0;
  if (t < 128 * 128){
    int c = t >> 7, k = t & 127;
    Wlt[t] = bf16r(W_lin[k * 128 + c]);
  } else if (t < 128 * 128 + 512 * 128){
    int u = t - 128 * 128; int c = u >> 7, k = u & 127;
    W1t[u] = bf16r(W1[k * 512 + c]);
  } else if (t < 128 * 128 + 512 * 128 + 128 * 512){
    int u = t - (128 * 128 + 512 * 128); int c = u >> 9, k = u & 511;
    W2t[u] = bf16r(W2[k * 128 + c]);
  } else {
    int u = t - (128 * 128 + 512 * 128 + 128 * 512);
    if (u < 128){
      float s = 0.f;
      for (int j = 0; j < 128; ++j) s += W_edge[u * 128 + j] * att_edge[j];
      we[u] = s;
    }
  }
}

// K2: LN1 + h = xn @ W_lin (Wlt in swizzled LDS) -> hq, dots, degree count
__global__ __launch_bounds__(256) void k_hgemm(const float* __restrict__ x,
                                               const unsigned short* __restrict__ Wlt,
                                               const float* __restrict__ ln1_g,
                                               const float* __restrict__ ln1_b,
                                               const float* __restrict__ att_src,
                                               const float* __restrict__ att_dst,
                                               const int* __restrict__ ei,
                                               unsigned short* __restrict__ hq,
                                               float* __restrict__ asrc,
                                               float* __restrict__ adst,
                                               int* __restrict__ cnt, int N, int E){
  __shared__ unsigned short wbuf[16384];   // 32KB swizzled copy of Wlt
#pragma unroll
  for (int r = 0; r < 8; ++r){
    int idx = r * 256 + threadIdx.x;
    int c = idx >> 4, kc = idx & 15;
    short8 w = *(const short8*)(Wlt + c * 128 + kc * 8);
    *(short8*)((char*)wbuf + c * 256 + ((kc * 16) ^ ((c & 7) << 4))) = w;
  }
  __syncthreads();
  int wid = threadIdx.x >> 6, lane = threadIdx.x & 63;
  int rb = blockIdx.x * 64 + wid * 16;
  int row = rb + (lane & 15);
  int rowc = row < N ? row : N - 1;
  int ksub = (lane >> 4) * 8;
  float v[4][8];
#pragma unroll
  for (int kb = 0; kb < 4; ++kb){
    float4 p0 = *(const float4*)(x + (size_t)rowc * 128 + kb * 32 + ksub);
    float4 p1 = *(const float4*)(x + (size_t)rowc * 128 + kb * 32 + ksub + 4);
    v[kb][0]=p0.x; v[kb][1]=p0.y; v[kb][2]=p0.z; v[kb][3]=p0.w;
    v[kb][4]=p1.x; v[kb][5]=p1.y; v[kb][6]=p1.z; v[kb][7]=p1.w;
  }
  float s = 0.f;
#pragma unroll
  for (int kb = 0; kb < 4; ++kb)
#pragma unroll
    for (int j = 0; j < 8; ++j) s += v[kb][j];
  s += __shfl_xor(s, 16); s += __shfl_xor(s, 32);
  float mu = s * (1.0f / 128.f);
  float q = 0.f;
#pragma unroll
  for (int kb = 0; kb < 4; ++kb)
#pragma unroll
    for (int j = 0; j < 8; ++j){ float d = v[kb][j] - mu; q += d * d; }
  q += __shfl_xor(q, 16); q += __shfl_xor(q, 32);
  float rstd = rsqrtf(q * (1.0f / 128.f) + 1e-5f);
  short8 a[4];
#pragma unroll
  for (int kb = 0; kb < 4; ++kb){
    float4 g0 = *(const float4*)(ln1_g + kb * 32 + ksub);
    float4 g1 = *(const float4*)(ln1_g + kb * 32 + ksub + 4);
    float4 b0 = *(const float4*)(ln1_b + kb * 32 + ksub);
    float4 b1 = *(const float4*)(ln1_b + kb * 32 + ksub + 4);
    float gg[8] = {g0.x,g0.y,g0.z,g0.w,g1.x,g1.y,g1.z,g1.w};
    float bb[8] = {b0.x,b0.y,b0.z,b0.w,b1.x,b1.y,b1.z,b1.w};
#pragma unroll
    for (int j = 0; j < 8; ++j)
      a[kb][j] = (short)bf16r((v[kb][j] - mu) * rstd * gg[j] + bb[j]);
  }
  f32x4 acc[8];
#pragma unroll
  for (int ct = 0; ct < 8; ++ct) acc[ct] = (f32x4){0.f, 0.f, 0.f, 0.f};
#pragma unroll
  for (int ct = 0; ct < 8; ++ct){
    int col = ct * 16 + (lane & 15);
    int cswz = (col & 7) << 4;
#pragma unroll
    for (int kb = 0; kb < 4; ++kb){
      short8 bf = *(const short8*)((const char*)wbuf + col * 256 +
                                   ((kb * 64 + ksub * 2) ^ cswz));
      acc[ct] = __builtin_amdgcn_mfma_f32_16x16x32_bf16(a[kb], bf, acc[ct], 0, 0, 0);
    }
  }
  int r0 = rb + (lane >> 4) * 4;
#pragma unroll
  for (int ct = 0; ct < 8; ++ct){
    int col = ct * 16 + (lane & 15);
#pragma unroll
    for (int j = 0; j < 4; ++j){
      int r = r0 + j;
      if (r < N) hq[(size_t)r * 128 + col] = bf16r(acc[ct][j]);
    }
  }
  float as_v[8], ad_v[8];
#pragma unroll
  for (int ct = 0; ct < 8; ++ct){
    int col = ct * 16 + (lane & 15);
    as_v[ct] = att_src[col];
    ad_v[ct] = att_dst[col];
  }
  float ps[4] = {0.f,0.f,0.f,0.f}, pd[4] = {0.f,0.f,0.f,0.f};
#pragma unroll
  for (int ct = 0; ct < 8; ++ct)
#pragma unroll
    for (int j = 0; j < 4; ++j){
      ps[j] += acc[ct][j] * as_v[ct];
      pd[j] += acc[ct][j] * ad_v[ct];
    }
#pragma unroll
  for (int m = 1; m < 16; m <<= 1)
#pragma unroll
    for (int j = 0; j < 4; ++j){
      ps[j] += __shfl_xor(ps[j], m);
      pd[j] += __shfl_xor(pd[j], m);
    }
  if ((lane & 15) == 0){
#pragma unroll
    for (int j = 0; j < 4; ++j){
      int r = r0 + j;
      if (r < N){ asrc[r] = ps[j]; adst[r] = pd[j]; }
    }
  }
  int t = blockIdx.x * blockDim.x + threadIdx.x;
  int stride = gridDim.x * blockDim.x;
  for (int e = t; e < E; e += stride) atomicAdd(&cnt[ei[E + e]], 1);
}

// K3: exclusive scan (self-sufficient, one node)
__global__ void k_escan(const int* __restrict__ cnt, int* __restrict__ start,
                        int* __restrict__ cursor, int N){
  int b = blockIdx.x, t = threadIdx.x;
  int base = b * 256;
  int acc = 0;
  for (int i = t; i < base; i += 256) acc += cnt[i];
  acc = wred_sumi(acc);
  __shared__ int wsum[4];
  if ((t & 63) == 0) wsum[t >> 6] = acc;
  __syncthreads();
  int s_off = wsum[0] + wsum[1] + wsum[2] + wsum[3];
  int i = base + t;
  int c = (i < N) ? cnt[i] : 0;
  __shared__ int sd[256];
  sd[t] = c;
  __syncthreads();
  for (int off = 1; off < 256; off <<= 1){
    int vv = (t >= off) ? sd[t - off] : 0;
    __syncthreads();
    sd[t] += vv;
    __syncthreads();
  }
  int st = s_off + sd[t] - c;
  if (i <= N) start[i] = st;
  if (i < N) cursor[i] = st;
}

// K4: fused edge logits + CSR scatter — at HBM roofline (~51us)
__global__ void k_edge_scatter(const float* __restrict__ ea, const int* __restrict__ ei,
                               const float* __restrict__ we, const float* __restrict__ asrc,
                               const float* __restrict__ adst, int* __restrict__ cursor,
                               int2* __restrict__ esa, int E){
  int gw = (blockIdx.x * blockDim.x + threadIdx.x) >> 6;
  int lane = threadIdx.x & 63;
  int e = gw * 2 + (lane >> 5);
  int li = lane & 31;
  if (e >= E) return;
  float4 v = *(const float4*)(ea + (size_t)e * 128 + li * 4);
  float4 w = *(const float4*)(we + li * 4);
  float s = v.x * w.x + v.y * w.y + v.z * w.z + v.w * w.w;
#pragma unroll
  for (int m = 16; m; m >>= 1) s += __shfl_xor(s, m);
  if (li == 0){
    int sn = ei[e], dn = ei[E + e];
    float al = asrc[sn] + adst[dn] + s;
    al = al > 0.f ? al : NEG_SLOPE * al;
    int slot = atomicAdd(&cursor[dn], 1);
    esa[slot] = make_int2(sn, __float_as_int(al));
  }
}

// K5: per-node softmax + gather + residual + LN2 — 4-wide unrolled gather
__global__ void k_agg(const float* __restrict__ x, const unsigned short* __restrict__ hq,
                      const int* __restrict__ start, const int2* __restrict__ esa,
                      const float* __restrict__ gat_bias,
                      const float* __restrict__ g2, const float* __restrict__ b2,
                      float* __restrict__ out, unsigned short* __restrict__ xn2q, int N){
  int n = (blockIdx.x * blockDim.x + threadIdx.x) >> 6;
  int lane = threadIdx.x & 63;
  if (n >= N) return;
  int beg = start[n], end = start[n + 1];
  float m = -1e30f;
  for (int i = beg + lane; i < end; i += 64) m = fmaxf(m, __int_as_float(esa[i].y));
  m = wred_max(m);
  float ds0 = 0.f, ds1 = 0.f, ds2 = 0.f, ds3 = 0.f;
  float a00 = 0.f, a01 = 0.f, a02 = 0.f, a03 = 0.f;
  float a10 = 0.f, a11 = 0.f, a12 = 0.f, a13 = 0.f;
  int s = beg;
  for (; s + 4 <= end; s += 4){
    int2 e0 = esa[s], e1 = esa[s + 1], e2 = esa[s + 2], e3 = esa[s + 3];
    float x0 = __expf(__int_as_float(e0.y) - m);
    float x1 = __expf(__int_as_float(e1.y) - m);
    float x2 = __expf(__int_as_float(e2.y) - m);
    float x3 = __expf(__int_as_float(e3.y) - m);
    unsigned int h0 = *(const unsigned int*)(hq + (size_t)e0.x * 128 + lane * 2);
    unsigned int h1 = *(const unsigned int*)(hq + (size_t)e1.x * 128 + lane * 2);
    unsigned int h2 = *(const unsigned int*)(hq + (size_t)e2.x * 128 + lane * 2);
    unsigned int h3 = *(const unsigned int*)(hq + (size_t)e3.x * 128 + lane * 2);
    ds0 += x0; ds1 += x1; ds2 += x2; ds3 += x3;
    a00 += x0 * bf2f(h0 & 0xffffu); a10 += x0 * bf2f(h0 >> 16);
    a01 += x1 * bf2f(h1 & 0xffffu); a11 += x1 * bf2f(h1 >> 16);
    a02 += x2 * bf2f(h2 & 0xffffu); a12 += x2 * bf2f(h2 >> 16);
    a03 += x3 * bf2f(h3 & 0xffffu); a13 += x3 * bf2f(h3 >> 16);
  }
  for (; s < end; ++s){
    int2 ev = esa[s];
    float ex = __expf(__int_as_float(ev.y) - m);
    unsigned int hv = *(const unsigned int*)(hq + (size_t)ev.x * 128 + lane * 2);
    ds0 += ex;
    a00 += ex * bf2f(hv & 0xffffu);
    a10 += ex * bf2f(hv >> 16);
  }
  float ds = (ds0 + ds1) + (ds2 + ds3);
  float a0 = (a00 + a01) + (a02 + a03);
  float a1 = (a10 + a11) + (a12 + a13);
  float inv = (end > beg) ? 1.f / fmaxf(ds, 1e-16f) : 0.f;
  a0 *= inv; a1 *= inv;
  float2 xv  = *(const float2*)(x + (size_t)n * 128 + lane * 2);
  float2 gbv = *(const float2*)(gat_bias + lane * 2);
  float r0 = xv.x + a0 + gbv.x;
  float r1 = xv.y + a1 + gbv.y;
  float mu = wred_sum(r0 + r1) * (1.0f / 128.f);
  float d0 = r0 - mu, d1 = r1 - mu;
  float var = wred_sum(d0 * d0 + d1 * d1) * (1.0f / 128.f);
  float rstd = rsqrtf(var + 1e-5f);
  float2 gv = *(const float2*)(g2 + lane * 2);
  float2 bv = *(const float2*)(b2 + lane * 2);
  float o0 = d0 * rstd * gv.x + bv.x;
  float o1 = d1 * rstd * gv.y + bv.y;
  *(float2*)(out + (size_t)n * 128 + lane * 2) = make_float2(r0, r1);
  unsigned int pk = (unsigned int)bf16r(o0) | ((unsigned int)bf16r(o1) << 16);
  *(unsigned int*)(xn2q + (size_t)n * 128 + lane * 2) = pk;
}

// K6: FFN v5 — chunk-owning blocks, fully LDS-resident operands, atomic out.
// grid = 4 chunks x 128 tile-blocks; block stages W1c+W2c (64KB) ONCE, then
// grid-strides ~12 tiles of 32 rows. Per tile: xn tile (8KB) staged COALESCED
// into swizzled LDS; phase A -> hid tile (8KB LDS); phase B -> f32 atomicAdd
// partials into out (b2 added by chunk 0). LDS 80KB, 512 thr -> 2 blocks/CU.
__global__ __launch_bounds__(512) void k_ffn(const unsigned short* __restrict__ xn2q,
                                             const unsigned short* __restrict__ W1t,
                                             const unsigned short* __restrict__ W2t,
                                             const float* __restrict__ b1,
                                             const float* __restrict__ b2,
                                             float* __restrict__ out, int N, int T){
  __shared__ unsigned short w1lds[128 * 128];  // 32KB [hcol_local][k] swizzled
  __shared__ unsigned short w2lds[128 * 128];  // 32KB [ocol][klocal] swizzled
  __shared__ unsigned short xnt[32 * 128];     // 8KB  [row][k] swizzled
  __shared__ unsigned short hidt[32 * 128];    // 8KB  [row][hcol_local] swizzled
  const int tid = threadIdx.x;
  const int chunk = blockIdx.x & 3;
  const int tb0 = blockIdx.x >> 2;             // 0..127
#pragma unroll
  for (int r = 0; r < 8; ++r){
    int idx = r * 512 + tid;                   // 4096: [w sel][cl(128)][kc(16)]
    int cl = (idx >> 4) & 127, kc = idx & 15;
    int dst = cl * 256 + ((kc * 16) ^ ((cl & 7) << 4));
    if (idx < 2048){
      short8 w1v = *(const short8*)(W1t + (size_t)(chunk * 128 + cl) * 128 + kc * 8);
      *(short8*)((char*)w1lds + dst) = w1v;
    } else {
      short8 w2v = *(const short8*)(W2t + (size_t)cl * 512 + chunk * 128 + kc * 8);
      *(short8*)((char*)w2lds + dst) = w2v;
    }
  }
  const int wid = tid >> 6, lane = tid & 63;
  const int i = lane & 15, g = lane >> 4;
  const int rw = wid >> 2;          // 0..1: 16-row half
  const int ca = wid & 3;           // 0..3: 32-col slice
  for (int t = tb0; t < T; t += 128){
    {
      int row = tid >> 4, kc = tid & 15;       // 512 chunks of 16B
      int trow = t * 32 + row;
      int trc = trow < N ? trow : N - 1;
      short8 xv = *(const short8*)(xn2q + (size_t)trc * 128 + kc * 8);
      *(short8*)((char*)xnt + row * 256 + ((kc * 16) ^ ((row & 7) << 4))) = xv;
    }
    __syncthreads();
#pragma unroll
    for (int ct = 0; ct < 2; ++ct){
      int hcol = ca * 32 + ct * 16 + i;        // local 0..127
      int cswz = (hcol & 7) << 4;
      f32x4 hacc = {0.f, 0.f, 0.f, 0.f};
#pragma unroll
      for (int kb = 0; kb < 4; ++kb){
        int arow = rw * 16 + i;
        short8 af = *(const short8*)((const char*)xnt + arow * 256 +
                                     ((kb * 64 + g * 16) ^ ((arow & 7) << 4)));
        short8 bf = *(const short8*)((const char*)w1lds + hcol * 256 +
                                     ((kb * 64 + g * 16) ^ cswz));
        hacc = __builtin_amdgcn_mfma_f32_16x16x32_bf16(af, bf, hacc, 0, 0, 0);
      }
      float bias = b1[chunk * 128 + hcol];
#pragma unroll
      for (int j = 0; j < 4; ++j){
        float v = hacc[j] + bias;
        v = v > 0.f ? v : 0.f;
        int nl = rw * 16 + g * 4 + j;
        *(unsigned short*)((char*)hidt + nl * 256 + ((hcol * 2) ^ ((nl & 7) << 4))) = bf16r(v);
      }
    }
    __syncthreads();
#pragma unroll
    for (int ct = 0; ct < 2; ++ct){
      int ocol = ca * 32 + ct * 16 + i;
      int cswz = (ocol & 7) << 4;
      f32x4 oacc = {0.f, 0.f, 0.f, 0.f};
#pragma unroll
      for (int kbl = 0; kbl < 4; ++kbl){
        int nrow = rw * 16 + i;
        short8 af = *(const short8*)((const char*)hidt + nrow * 256 +
                                     ((kbl * 64 + g * 16) ^ ((nrow & 7) << 4)));
        short8 bf = *(const short8*)((const char*)w2lds + ocol * 256 +
                                     ((kbl * 64 + g * 16) ^ cswz));
        oacc = __builtin_amdgcn_mfma_f32_16x16x32_bf16(af, bf, oacc, 0, 0, 0);
      }
      float bias = (chunk == 0) ? b2[ocol] : 0.f;
#pragma unroll
      for (int j = 0; j < 4; ++j){
        int row = t * 32 + rw * 16 + g * 4 + j;
        if (row < N) atomicAdd(&out[(size_t)row * 128 + ocol], oacc[j] + bias);
      }
    }
    __syncthreads();   // protect xnt/hidt before next tile's staging
  }
}

extern "C" void kernel_launch(void* const* d_in, const int* in_sizes, int n_in,
                              void* d_out, int out_size, void* d_ws, size_t ws_size,
                              hipStream_t stream){
  const float* x        = (const float*)d_in[0];
  const int*   ei       = (const int*)  d_in[1];
  const float* ea       = (const float*)d_in[2];
  const float* ln1_g    = (const float*)d_in[3];
  const float* ln1_b    = (const float*)d_in[4];
  const float* W_lin    = (const float*)d_in[5];
  const float* att_src  = (const float*)d_in[6];
  const float* att_dst  = (const float*)d_in[7];
  const float* W_edge   = (const float*)d_in[8];
  const float* att_edge = (const float*)d_in[9];
  const float* gat_bias = (const float*)d_in[10];
  const float* ln2_g    = (const float*)d_in[11];
  const float* ln2_b    = (const float*)d_in[12];
  const float* W1       = (const float*)d_in[13];
  const float* b1       = (const float*)d_in[14];
  const float* W2       = (const float*)d_in[15];
  const float* b2       = (const float*)d_in[16];

  const int N = in_sizes[0] / 128;
  const int E = in_sizes[2] / 128;
  const int T32 = (N + 31) / 32;
  float* out = (float*)d_out;

  char* pp = (char*)d_ws;
  auto carve = [&](size_t bytes) -> char* {
    char* r = pp; pp += (bytes + 255) & ~(size_t)255; return r;
  };
  unsigned short* hq     = (unsigned short*)carve((size_t)N * 128 * 2);
  unsigned short* xn2q   = (unsigned short*)carve((size_t)N * 128 * 2);
  float*          asrc   = (float*)carve((size_t)N * 4);
  float*          adst   = (float*)carve((size_t)N * 4);
  int2*           esa    = (int2*)carve((size_t)E * 8);
  int*            cnt    = (int*)carve((size_t)N * 4);
  int*            cursor = (int*)carve((size_t)N * 4);
  int*            start  = (int*)carve((size_t)(N + 1) * 4);
  unsigned short* Wlt    = (unsigned short*)carve(128 * 128 * 2);
  unsigned short* W1t    = (unsigned short*)carve(512 * 128 * 2);
  unsigned short* W2t    = (unsigned short*)carve(128 * 512 * 2);
  float*          we     = (float*)carve(128 * 4);

  k_prep0<<<(128*128 + 512*128 + 128*512 + 128 + 255) / 256, 256, 0, stream>>>(
      W_lin, W1, W2, W_edge, att_edge, Wlt, W1t, W2t, we, cnt, N);
  k_hgemm<<<(N + 63) / 64, 256, 0, stream>>>(x, Wlt, ln1_g, ln1_b, att_src, att_dst, ei,
                                             hq, asrc, adst, cnt, N, E);
  k_escan<<<N / 256 + 1, 256, 0, stream>>>(cnt, start, cursor, N);
  k_edge_scatter<<<(E + 7) / 8, 256, 0, stream>>>(ea, ei, we, asrc, adst, cursor, esa, E);
  k_agg<<<(N + 3) / 4, 256, 0, stream>>>(x, hq, start, esa, gat_bias, ln2_g, ln2_b,
                                         out, xn2q, N);
  k_ffn<<<512, 512, 0, stream>>>(xn2q, W1t, W2t, b1, b2, out, N, T32);
}